// Round 5
// baseline (229.990 us; speedup 1.0000x reference)
//
#include <hip/hip_runtime.h>
#include <stdint.h>

// Problem constants (match reference)
#define T_TOK 1024
#define HDIM  1024
#define IDIM  512
#define NEXP  16
#define ISH   1024       // shared intermediate
#define MAXT128  48      // sum ceil(cnt_e/128) <= 4096/128 + 16 = 48
#define HSLOTS   6144    // 48 * 128 padded routed rows

typedef _Float16 f16;
typedef __attribute__((ext_vector_type(8))) _Float16 f16x8;
typedef __attribute__((ext_vector_type(4))) _Float16 f16x4;
typedef __attribute__((ext_vector_type(4))) float    f32x4;

// ---- async global->LDS, 16B per lane. LDS dst is wave-uniform base; HW adds lane*16.
__device__ __forceinline__ void gld16(const void* g, void* l) {
  __builtin_amdgcn_global_load_lds(
      (__attribute__((address_space(1))) void*)(uintptr_t)g,
      (__attribute__((address_space(3))) void*)(uint32_t)(uintptr_t)l,
      16, 0, 0);
}

// ---- LDS tile rows of 64 halfs; 16B chunks XOR-swizzled by (row&7):
// contiguous global_load_lds staging AND ds_read_b128 frag reads both 2-way (free).
__device__ __forceinline__ f16x8 ldsfrag(const f16* buf, int row, int lch) {
  int phys = lch ^ (row & 7);
  return *(const f16x8*)(buf + row * 64 + phys * 8);
}

// =============== transpose+convert: fp32 [R,C] -> f16 [C,R], flat tile list ===============
// 6912 tiles of 64x64; 4 tiles per block -> 1728 blocks (no no-op dispatch).
__global__ __launch_bounds__(256) void transpose_all(
    const float* __restrict__ wg, const float* __restrict__ wu, const float* __restrict__ wd,
    const float* __restrict__ sg, const float* __restrict__ su, const float* __restrict__ sd,
    f16* __restrict__ wgT, f16* __restrict__ wuT, f16* __restrict__ wdT,
    f16* __restrict__ sgT, f16* __restrict__ suT, f16* __restrict__ sdT) {
  __shared__ float tile[64][65];                   // +1 pad
  int t = threadIdx.x;
#pragma unroll
  for (int it = 0; it < 4; it++) {
    int ti = blockIdx.x * 4 + it;
    const float* src; f16* dst; int R, C, within, clog;
    if (ti < 2048)      { int e2 = ti >> 7; within = ti & 127; R = HDIM; C = IDIM; clog = 3;
                          src = wg + (size_t)e2 * HDIM * IDIM; dst = wgT + (size_t)e2 * HDIM * IDIM; }
    else if (ti < 4096) { int u = ti - 2048; int e2 = u >> 7; within = u & 127; R = HDIM; C = IDIM; clog = 3;
                          src = wu + (size_t)e2 * HDIM * IDIM; dst = wuT + (size_t)e2 * HDIM * IDIM; }
    else if (ti < 6144) { int u = ti - 4096; int e2 = u >> 7; within = u & 127; R = IDIM; C = HDIM; clog = 4;
                          src = wd + (size_t)e2 * IDIM * HDIM; dst = wdT + (size_t)e2 * IDIM * HDIM; }
    else                { int u = ti - 6144; int which = u >> 8; within = u & 255; R = HDIM; C = ISH; clog = 4;
                          src = which == 0 ? sg : (which == 1 ? su : sd);
                          dst = which == 0 ? sgT : (which == 1 ? suT : sdT); }
    int r0 = (within >> clog) * 64, c0 = (within & ((1 << clog) - 1)) * 64;

    if (it) __syncthreads();                       // protect LDS reuse
    int lr = t >> 4, c4 = (t & 15) * 4;
#pragma unroll
    for (int pass = 0; pass < 4; pass++) {
      int r = pass * 16 + lr;
      float4 v = *(const float4*)(src + (size_t)(r0 + r) * C + (c0 + c4));
      tile[r][c4 + 0] = v.x; tile[r][c4 + 1] = v.y;
      tile[r][c4 + 2] = v.z; tile[r][c4 + 3] = v.w;
    }
    __syncthreads();
    int oc = t >> 2, or0 = (t & 3) * 16;
    f16x8 v0, v1;
#pragma unroll
    for (int i = 0; i < 8; i++) {
      v0[i] = (f16)tile[or0 + i][oc];
      v1[i] = (f16)tile[or0 + 8 + i][oc];
    }
    f16* dp = dst + (size_t)(c0 + oc) * R + r0 + or0;
    *(f16x8*)dp = v0;
    *(f16x8*)(dp + 8) = v1;
  }
}

// =============== router GEMV (also emits xh = f16(x)): 4 tokens/block ===============
__global__ __launch_bounds__(256) void router_kernel(
    const float* __restrict__ x, const float* __restrict__ rw, const float* __restrict__ ebias,
    f16* __restrict__ xh, int* __restrict__ topk_i, float* __restrict__ topk_w) {
  int wave = threadIdx.x >> 6, l = threadIdx.x & 63;
  int t = blockIdx.x * 4 + wave;
  float acc[16];
#pragma unroll
  for (int e = 0; e < 16; e++) acc[e] = 0.f;
#pragma unroll
  for (int i = 0; i < 4; i++) {
    int k = i * 256 + l * 4;
    float4 xv = *(const float4*)(x + (size_t)t * HDIM + k);
    f16x4 h = { (f16)xv.x, (f16)xv.y, (f16)xv.z, (f16)xv.w };
    *(f16x4*)(xh + (size_t)t * HDIM + k) = h;
    const float* xp = &xv.x;
#pragma unroll
    for (int j = 0; j < 4; j++) {
      float xj = xp[j];
      const float4* w4 = (const float4*)(rw + (size_t)(k + j) * 16);
#pragma unroll
      for (int q = 0; q < 4; q++) {
        float4 w = w4[q];
        acc[q*4+0] += xj * w.x; acc[q*4+1] += xj * w.y;
        acc[q*4+2] += xj * w.z; acc[q*4+3] += xj * w.w;
      }
    }
  }
#pragma unroll
  for (int off = 32; off >= 1; off >>= 1)
#pragma unroll
    for (int e = 0; e < 16; e++) acc[e] += __shfl_xor(acc[e], off, 64);

  if (l == 0) {
    float s[16], sc[16];
#pragma unroll
    for (int e = 0; e < 16; e++) {
      s[e] = 1.f / (1.f + __expf(-acc[e]));       // sigmoid scores (weights)
      sc[e] = s[e] + ebias[e];                     // biased (selection only)
    }
    float gs[4];
#pragma unroll
    for (int g = 0; g < 4; g++) {                  // sum of top-2 per group of 4
      float a = -1e30f, b = -1e30f;
#pragma unroll
      for (int j = 0; j < 4; j++) {
        float v = sc[g*4 + j];
        if (v > a) { b = a; a = v; } else if (v > b) { b = v; }
      }
      gs[g] = a + b;
    }
    int g1 = 0;
    for (int g = 1; g < 4; g++) if (gs[g] > gs[g1]) g1 = g;   // ties -> lowest idx
    int g2 = -1;
    for (int g = 0; g < 4; g++) if (g != g1 && (g2 < 0 || gs[g] > gs[g2])) g2 = g;
    float masked[16];
#pragma unroll
    for (int e = 0; e < 16; e++) {
      int g = e >> 2;
      masked[e] = (g == g1 || g == g2) ? sc[e] : 0.0f;        // ref: unselected -> 0.0
    }
    int idx[4]; float wv[4]; float denom = 1e-20f;
#pragma unroll
    for (int j = 0; j < 4; j++) {
      int best = 0; float bv = masked[0];
      for (int e = 1; e < 16; e++) if (masked[e] > bv) { bv = masked[e]; best = e; }
      idx[j] = best; wv[j] = s[best]; denom += s[best];
      masked[best] = -1e30f;
    }
#pragma unroll
    for (int j = 0; j < 4; j++) {
      topk_i[t * 4 + j] = idx[j];
      topk_w[t * 4 + j] = wv[j] / denom * 2.5f;   // fold ROUTED_SCALE
    }
  }
}

// =============== scatter: per-expert lists + 128-row tiles + slot map ===============
__global__ __launch_bounds__(1024) void scatter_kernel(
    const int* __restrict__ tki,
    int* __restrict__ tok, int* __restrict__ slotmap,
    int* __restrict__ tile_e, int* __restrict__ tile_srow,
    int* __restrict__ tile_hb, int* __restrict__ ntl) {
  __shared__ int lcnt[NEXP], lpos[NEXP], lbase[NEXP];
  int t = threadIdx.x;                   // one thread per token
  if (t < NEXP) { lcnt[t] = 0; lpos[t] = 0; }
  __syncthreads();
  int idx[4];
#pragma unroll
  for (int j = 0; j < 4; j++) idx[j] = tki[t*4+j];
#pragma unroll
  for (int j = 0; j < 4; j++) atomicAdd(&lcnt[idx[j]], 1);
  __syncthreads();
  if (t == 0) {                          // tile metadata (tiny serial)
    int total = 0, slots = 0;
    for (int e = 0; e < NEXP; e++) {
      int c = lcnt[e], nt = (c + 127) >> 7;
      lbase[e] = slots;
      for (int j = 0; j < nt; j++) {
        tile_e[total] = e; tile_srow[total] = j * 128; tile_hb[total] = slots + j * 128; total++;
      }
      slots += nt * 128;
    }
    ntl[0] = total;
  }
  __syncthreads();
#pragma unroll
  for (int j = 0; j < 4; j++) {
    int slot = atomicAdd(&lpos[idx[j]], 1);
    tok[idx[j] * T_TOK + slot] = t;
    slotmap[t * 4 + j] = lbase[idx[j]] + slot;   // hbuf/odown row of this assignment
  }
  __syncthreads();
  // padding rows (up to 127/expert) gather token 0; results never read by combine
  int e = t >> 6, s = t & 63;
  int c = lcnt[e];
  int top = ((c + 127) >> 7) << 7;
  for (int s2 = c + s; s2 < top; s2 += 64) tok[e * T_TOK + s2] = 0;
}

// =============== GEMM cores ===============
__device__ __forceinline__ f32x4 mfma16(f16x8 a, f16x8 b, f32x4 c) {
  return __builtin_amdgcn_mfma_f32_16x16x32_f16(a, b, c, 0, 0, 0);
}

// gate+up, TM=128 TN=64 BK=64, 4 waves 2x2 (wave = 64m x 32n), fused silu.
// shared: blocks 0..127; routed gather: blocks 128..511 (48 tiles x 8 nblk)
__global__ __launch_bounds__(256) void gu_all(
    const f16* __restrict__ xh,
    const f16* __restrict__ sgT, const f16* __restrict__ suT, f16* __restrict__ hsh,
    const f16* __restrict__ wgT, const f16* __restrict__ wuT, f16* __restrict__ hbuf,
    const int* __restrict__ tile_e, const int* __restrict__ tile_srow,
    const int* __restrict__ tile_hb, const int* __restrict__ ntl,
    const int* __restrict__ tok) {
  int b = blockIdx.x;
  const f16 *Bg, *Bu; f16* Hdst;
  int e = 0, srow = 0, mbase, n0, N;
  bool gather = (b >= 128);
  if (!gather) {
    Bg = sgT; Bu = suT; Hdst = hsh; N = ISH;
    mbase = (b >> 4) * 128; n0 = (b & 15) * 64;
  } else {
    int rb = b - 128, by = rb >> 3;
    if (by >= ntl[0]) return;
    e = tile_e[by]; srow = tile_srow[by]; mbase = tile_hb[by];
    size_t bo = (size_t)e * IDIM * HDIM;
    Bg = wgT + bo; Bu = wuT + bo; Hdst = hbuf; N = IDIM;
    n0 = (rb & 7) * 64;
  }
  const int K = HDIM;

  __shared__ f16 As[128 * 64], Bgs[64 * 64], Bus[64 * 64];   // 32 KB

  int tid = threadIdx.x, lane = tid & 63, wave = tid >> 6;
  int quad = lane >> 4, l15 = lane & 15;
  int r = lane >> 3, p = lane & 7;

  // 32 staging instrs: A:16 (rows 0..127), Bg:8, Bu:8 -> 8 per wave
  const f16* gb[8]; f16* lb[8];
#pragma unroll
  for (int jj = 0; jj < 8; jj++) {
    int j = wave * 8 + jj;
    int kcol = (p ^ r) << 3;                       // swizzled k-chunk
    if (j < 16) {
      int row = j * 8 + r;
      int grow = gather ? tok[e * T_TOK + srow + row] : (mbase + row);
      gb[jj] = xh + (size_t)grow * K + kcol;       lb[jj] = (f16*)As + (j << 9);
    } else if (j < 24) {
      int i = j - 16, row = i * 8 + r;
      gb[jj] = Bg + (size_t)(n0 + row) * K + kcol; lb[jj] = (f16*)Bgs + (i << 9);
    } else {
      int i = j - 24, row = i * 8 + r;
      gb[jj] = Bu + (size_t)(n0 + row) * K + kcol; lb[jj] = (f16*)Bus + (i << 9);
    }
  }

  int wr = wave >> 1, wc = wave & 1;               // wave tile: 64m x 32n
  f32x4 zero = {0.f, 0.f, 0.f, 0.f};
  f32x4 aG[4][2], aU[4][2];
#pragma unroll
  for (int mi = 0; mi < 4; mi++)
#pragma unroll
    for (int ni = 0; ni < 2; ni++) { aG[mi][ni] = zero; aU[mi][ni] = zero; }

  for (int kt = 0; kt < K; kt += 64) {
    __syncthreads();
#pragma unroll
    for (int jj = 0; jj < 8; jj++) gld16(gb[jj] + kt, lb[jj]);
    __syncthreads();
#pragma unroll
    for (int ks = 0; ks < 2; ks++) {
      int lch = (ks << 2) + quad;
      f16x8 a[4], g[2], u[2];
#pragma unroll
      for (int mi = 0; mi < 4; mi++) a[mi] = ldsfrag(As, 64 * wr + 16 * mi + l15, lch);
#pragma unroll
      for (int ni = 0; ni < 2; ni++) {
        g[ni] = ldsfrag(Bgs, 32 * wc + 16 * ni + l15, lch);
        u[ni] = ldsfrag(Bus, 32 * wc + 16 * ni + l15, lch);
      }
#pragma unroll
      for (int mi = 0; mi < 4; mi++)
#pragma unroll
        for (int ni = 0; ni < 2; ni++) {
          aG[mi][ni] = mfma16(a[mi], g[ni], aG[mi][ni]);
          aU[mi][ni] = mfma16(a[mi], u[ni], aU[mi][ni]);
        }
    }
  }
#pragma unroll
  for (int mi = 0; mi < 4; mi++)
#pragma unroll
    for (int ni = 0; ni < 2; ni++)
#pragma unroll
      for (int rg = 0; rg < 4; rg++) {
        int m = 64 * wr + 16 * mi + (quad << 2) + rg;   // C/D: row = quad*4+reg
        int n = n0 + 32 * wc + 16 * ni + l15;           //      col = lane&15
        float g = aG[mi][ni][rg], u = aU[mi][ni][rg];
        float val = (g / (1.f + __expf(-g))) * u;
        Hdst[(size_t)(mbase + m) * N + n] = (f16)val;
      }
}

// down proj, TM=128 TN=128 BK=64, 4 waves 2x2 (wave = 64x64).
// shared: blocks 0..63 -> out fp32; routed: blocks 64..447 -> odown f16
__global__ __launch_bounds__(256) void down_all(
    const f16* __restrict__ hsh, const f16* __restrict__ sdT,
    const f16* __restrict__ hbuf, const f16* __restrict__ wdT,
    float* __restrict__ out, f16* __restrict__ odown,
    const int* __restrict__ tile_hb, const int* __restrict__ tile_e,
    const int* __restrict__ ntl) {
  int b = blockIdx.x;
  bool routed = (b >= 64);
  const f16 *A, *B; int K, abase, n0;
  if (!routed) {
    A = hsh; B = sdT; K = ISH;
    abase = (b >> 3) * 128; n0 = (b & 7) * 128;
  } else {
    int rb = b - 64, by = rb >> 3;
    if (by >= ntl[0]) return;
    abase = tile_hb[by];
    A = hbuf; B = wdT + (size_t)tile_e[by] * HDIM * IDIM; K = IDIM;
    n0 = (rb & 7) * 128;
  }

  __shared__ f16 As[128 * 64], Bs[128 * 64];       // 32 KB

  int tid = threadIdx.x, lane = tid & 63, wave = tid >> 6;
  int quad = lane >> 4, l15 = lane & 15;
  int r = lane >> 3, p = lane & 7;

  // 32 staging instrs: A:16, B:16 -> 8 per wave
  const f16* gb[8]; f16* lb[8];
#pragma unroll
  for (int jj = 0; jj < 8; jj++) {
    int j = wave * 8 + jj;
    int kcol = (p ^ r) << 3;
    if (j < 16) {
      int row = j * 8 + r;
      gb[jj] = A + (size_t)(abase + row) * K + kcol; lb[jj] = (f16*)As + (j << 9);
    } else {
      int i = j - 16, row = i * 8 + r;
      gb[jj] = B + (size_t)(n0 + row) * K + kcol;    lb[jj] = (f16*)Bs + (i << 9);
    }
  }

  int wr = wave >> 1, wc = wave & 1;               // wave tile: 64 x 64
  f32x4 zero = {0.f, 0.f, 0.f, 0.f};
  f32x4 ac[4][4];
#pragma unroll
  for (int mi = 0; mi < 4; mi++)
#pragma unroll
    for (int ni = 0; ni < 4; ni++) ac[mi][ni] = zero;

  for (int kt = 0; kt < K; kt += 64) {
    __syncthreads();
#pragma unroll
    for (int jj = 0; jj < 8; jj++) gld16(gb[jj] + kt, lb[jj]);
    __syncthreads();
#pragma unroll
    for (int ks = 0; ks < 2; ks++) {
      int lch = (ks << 2) + quad;
      f16x8 a[4], bb[4];
#pragma unroll
      for (int mi = 0; mi < 4; mi++) a[mi] = ldsfrag(As, 64 * wr + 16 * mi + l15, lch);
#pragma unroll
      for (int ni = 0; ni < 4; ni++) bb[ni] = ldsfrag(Bs, 64 * wc + 16 * ni + l15, lch);
#pragma unroll
      for (int mi = 0; mi < 4; mi++)
#pragma unroll
        for (int ni = 0; ni < 4; ni++)
          ac[mi][ni] = mfma16(a[mi], bb[ni], ac[mi][ni]);
    }
  }
#pragma unroll
  for (int mi = 0; mi < 4; mi++)
#pragma unroll
    for (int ni = 0; ni < 4; ni++)
#pragma unroll
      for (int rg = 0; rg < 4; rg++) {
        int m = 64 * wr + 16 * mi + (quad << 2) + rg;
        int n = n0 + 64 * wc + 16 * ni + l15;
        if (routed) odown[(size_t)(abase + m) * HDIM + n] = (f16)ac[mi][ni][rg];
        else        out  [(size_t)(abase + m) * HDIM + n] = ac[mi][ni][rg];
      }
}

// =============== combine: out[t] += sum_j w_j * odown[slot(t,j)] ===============
__global__ __launch_bounds__(256) void combine_kernel(
    const f16* __restrict__ odown, const int* __restrict__ slotmap,
    const float* __restrict__ tkw, float* __restrict__ out) {
  int t = blockIdx.x;
  __shared__ int ss[4]; __shared__ float sw[4];
  if (threadIdx.x < 4) {
    ss[threadIdx.x] = slotmap[t * 4 + threadIdx.x];
    sw[threadIdx.x] = tkw[t * 4 + threadIdx.x];
  }
  __syncthreads();
  int h = threadIdx.x * 4;
  float4 acc = *(const float4*)(out + (size_t)t * HDIM + h);
#pragma unroll
  for (int j = 0; j < 4; j++) {
    f16x4 v = *(const f16x4*)(odown + (size_t)ss[j] * HDIM + h);
    float wj = sw[j];
    acc.x += wj * (float)v[0]; acc.y += wj * (float)v[1];
    acc.z += wj * (float)v[2]; acc.w += wj * (float)v[3];
  }
  *(float4*)(out + (size_t)t * HDIM + h) = acc;
}

// =============== launch ===============
extern "C" void kernel_launch(void* const* d_in, const int* in_sizes, int n_in,
                              void* d_out, int out_size, void* d_ws, size_t ws_size,
                              hipStream_t stream) {
  const float* x  = (const float*)d_in[0];
  const float* rw = (const float*)d_in[1];
  const float* eb = (const float*)d_in[2];
  const float* wg = (const float*)d_in[3];
  const float* wu = (const float*)d_in[4];
  const float* wd = (const float*)d_in[5];
  const float* sg = (const float*)d_in[6];
  const float* su = (const float*)d_in[7];
  const float* sd = (const float*)d_in[8];
  float* out = (float*)d_out;
  (void)in_sizes; (void)n_in; (void)out_size; (void)ws_size;

  char* w = (char*)d_ws;
  size_t off = 0;
  auto alloc = [&](size_t b) { void* p = w + off; off = (off + b + 255) & ~(size_t)255; return p; };

  f16* xh   = (f16*)alloc((size_t)T_TOK * HDIM * 2);
  f16* wgT  = (f16*)alloc((size_t)NEXP * IDIM * HDIM * 2);
  f16* wuT  = (f16*)alloc((size_t)NEXP * IDIM * HDIM * 2);
  f16* wdT  = (f16*)alloc((size_t)NEXP * HDIM * IDIM * 2);
  f16* sgT  = (f16*)alloc((size_t)ISH * HDIM * 2);
  f16* suT  = (f16*)alloc((size_t)ISH * HDIM * 2);
  f16* sdT  = (f16*)alloc((size_t)HDIM * ISH * 2);
  f16* hbuf = (f16*)alloc((size_t)HSLOTS * IDIM * 2);
  f16* hsh  = (f16*)alloc((size_t)T_TOK * ISH * 2);
  int* topk_i = (int*)alloc((size_t)T_TOK * 4 * 4);
  float* topk_w = (float*)alloc((size_t)T_TOK * 4 * 4);
  int* tok  = (int*)alloc((size_t)NEXP * T_TOK * 4);
  int* slotmap = (int*)alloc((size_t)T_TOK * 4 * 4);
  int* tile_e    = (int*)alloc(MAXT128 * 4);
  int* tile_srow = (int*)alloc(MAXT128 * 4);
  int* tile_hb   = (int*)alloc(MAXT128 * 4);
  int* ntl       = (int*)alloc(16);
  // odown (f16, HSLOTS x HDIM = 12.6 MB) aliases wgT (16 MB): wgT dead after gu_all.
  f16* odown = (f16*)wgT;

  transpose_all<<<1728, 256, 0, stream>>>(wg, wu, wd, sg, su, sd,
                                          wgT, wuT, wdT, sgT, suT, sdT);
  router_kernel<<<T_TOK / 4, 256, 0, stream>>>(x, rw, eb, xh, topk_i, topk_w);
  scatter_kernel<<<1, 1024, 0, stream>>>(topk_i, tok, slotmap,
                                         tile_e, tile_srow, tile_hb, ntl);
  // shared gu (128 blocks) + routed gu (384) in one dispatch
  gu_all<<<128 + MAXT128 * 8, 256, 0, stream>>>(
      xh, sgT, suT, hsh, wgT, wuT, hbuf, tile_e, tile_srow, tile_hb, ntl, tok);
  // shared down (64) -> out fp32; routed down (384) -> odown f16
  down_all<<<64 + MAXT128 * 8, 256, 0, stream>>>(
      hsh, sdT, hbuf, wdT, out, odown, tile_hb, tile_e, ntl);
  // out[t] += sum_j w_j * odown[slot]
  combine_kernel<<<T_TOK, 256, 0, stream>>>(odown, slotmap, topk_w, out);
}

// Round 6
// 229.125 us; speedup vs baseline: 1.0038x; 1.0038x over previous
//
#include <hip/hip_runtime.h>
#include <stdint.h>

// Problem constants (match reference)
#define T_TOK 1024
#define HDIM  1024
#define IDIM  512
#define NEXP  16
#define ISH   1024       // shared intermediate
#define MAXT128  48      // sum ceil(cnt_e/128) <= 4096/128 + 16 = 48
#define HSLOTS   6144    // 48 * 128 padded routed rows
#define NTTILES  1728    // 128x128 transpose tiles

typedef _Float16 f16;
typedef __attribute__((ext_vector_type(8))) _Float16 f16x8;
typedef __attribute__((ext_vector_type(4))) _Float16 f16x4;
typedef __attribute__((ext_vector_type(2))) _Float16 f16x2;
typedef __attribute__((ext_vector_type(4))) float    f32x4;

// ---- async global->LDS, 16B per lane. LDS dst is wave-uniform base; HW adds lane*16.
__device__ __forceinline__ void gld16(const void* g, void* l) {
  __builtin_amdgcn_global_load_lds(
      (__attribute__((address_space(1))) void*)(uintptr_t)g,
      (__attribute__((address_space(3))) void*)(uint32_t)(uintptr_t)l,
      16, 0, 0);
}

// ---- GEMM LDS tile rows of 64 halfs; 16B chunks XOR-swizzled by (row&7).
__device__ __forceinline__ f16x8 ldsfrag(const f16* buf, int row, int lch) {
  int phys = lch ^ (row & 7);
  return *(const f16x8*)(buf + row * 64 + phys * 8);
}

// =============== prep_all: transpose tiles (blocks 0..1727) + router (1728..1983) ===============
// Transpose: 128x128 tiles, fp32 [R,C] -> f16 [C,R]. DRAM segments: 512B reads,
// 256B writes (vs 256/128 at 64-tiles) — attacks the activate-bound 2.4 TB/s plateau.
// LDS tile f16 stride 130: phase-1 b32 writes 2-way (free); phase-2 b32 reads 4-way (1.58x).
__global__ __launch_bounds__(256) void prep_all(
    const float* __restrict__ wg, const float* __restrict__ wu, const float* __restrict__ wd,
    const float* __restrict__ sg, const float* __restrict__ su, const float* __restrict__ sd,
    f16* __restrict__ wgT, f16* __restrict__ wuT, f16* __restrict__ wdT,
    f16* __restrict__ sgT, f16* __restrict__ suT, f16* __restrict__ sdT,
    const float* __restrict__ x, const float* __restrict__ rw, const float* __restrict__ ebias,
    f16* __restrict__ xh, int* __restrict__ topk_i, float* __restrict__ topk_w) {
  int b = blockIdx.x;
  if (b < NTTILES) {
    // ---- transpose one 128x128 tile ----
    const float* src; f16* dst; int R, C, rt, ct;
    if (b < 1024) {        // wg | wu: [1024, 512], 32 tiles each (8r x 4c)
      int mat = b >> 5, wi = b & 31;
      const float* s0 = (mat < 16) ? wg : wu;
      f16* d0 = (mat < 16) ? wgT : wuT;
      int e = mat & 15;
      src = s0 + (size_t)e * HDIM * IDIM; dst = d0 + (size_t)e * HDIM * IDIM;
      R = HDIM; C = IDIM; rt = wi >> 2; ct = wi & 3;
    } else if (b < 1536) { // wd: [512, 1024], 32 tiles each (4r x 8c)
      int u = b - 1024; int e = u >> 5, wi = u & 31;
      src = wd + (size_t)e * IDIM * HDIM; dst = wdT + (size_t)e * IDIM * HDIM;
      R = IDIM; C = HDIM; rt = wi >> 3; ct = wi & 7;
    } else {               // sg | su | sd: [1024,1024], 64 tiles each (8r x 8c)
      int u = b - 1536; int which = u >> 6, wi = u & 63;
      src = which == 0 ? sg : (which == 1 ? su : sd);
      dst = which == 0 ? sgT : (which == 1 ? suT : sdT);
      R = HDIM; C = ISH; rt = wi >> 3; ct = wi & 7;
    }
    int r0 = rt * 128, c0 = ct * 128;

    __shared__ f16 tl[128 * 130];
    int t = threadIdx.x;
    // phase 1: 16 x float4 loads (two 512B row-segments per wave instr), cvt, b32 LDS writes
    int rr = t >> 5, c4 = (t & 31) * 4;
#pragma unroll
    for (int p = 0; p < 16; p++) {
      int r = p * 8 + rr;
      float4 v = *(const float4*)(src + (size_t)(r0 + r) * C + (c0 + c4));
      f16x2 a = { (f16)v.x, (f16)v.y };
      f16x2 b2 = { (f16)v.z, (f16)v.w };
      *(f16x2*)(tl + r * 130 + c4)     = a;
      *(f16x2*)(tl + r * 130 + c4 + 2) = b2;
    }
    __syncthreads();
    // phase 2: b32 column-pair reads, assemble f16x8 chunks, 16B stores
    // lanes i=0..15 cover r=8i.. -> each wave instr stores 4 x 256B contiguous segments
    int i = t & 15, cb = t >> 4;
    int rr0 = i * 8;
#pragma unroll
    for (int u = 0; u < 4; u++) {
      int cp = cb + 16 * u;              // column pair index (c = 2*cp)
      unsigned wv[8];
#pragma unroll
      for (int k = 0; k < 8; k++)
        wv[k] = *(const unsigned*)(tl + (rr0 + k) * 130 + 2 * cp);
      uint4 lo, hi;
      lo.x = (wv[0] & 0xffffu) | (wv[1] << 16);
      lo.y = (wv[2] & 0xffffu) | (wv[3] << 16);
      lo.z = (wv[4] & 0xffffu) | (wv[5] << 16);
      lo.w = (wv[6] & 0xffffu) | (wv[7] << 16);
      hi.x = (wv[0] >> 16) | (wv[1] & 0xffff0000u);
      hi.y = (wv[2] >> 16) | (wv[3] & 0xffff0000u);
      hi.z = (wv[4] >> 16) | (wv[5] & 0xffff0000u);
      hi.w = (wv[6] >> 16) | (wv[7] & 0xffff0000u);
      int c = 2 * cp;
      *(uint4*)(dst + (size_t)(c0 + c)     * R + r0 + rr0) = lo;
      *(uint4*)(dst + (size_t)(c0 + c + 1) * R + r0 + rr0) = hi;
    }
    return;
  }

  // ---- router: 4 tokens per block ----
  int wave = threadIdx.x >> 6, l = threadIdx.x & 63;
  int t = (b - NTTILES) * 4 + wave;
  float acc[16];
#pragma unroll
  for (int e = 0; e < 16; e++) acc[e] = 0.f;
#pragma unroll
  for (int i = 0; i < 4; i++) {
    int k = i * 256 + l * 4;
    float4 xv = *(const float4*)(x + (size_t)t * HDIM + k);
    f16x4 h = { (f16)xv.x, (f16)xv.y, (f16)xv.z, (f16)xv.w };
    *(f16x4*)(xh + (size_t)t * HDIM + k) = h;
    const float* xp = &xv.x;
#pragma unroll
    for (int j = 0; j < 4; j++) {
      float xj = xp[j];
      const float4* w4 = (const float4*)(rw + (size_t)(k + j) * 16);
#pragma unroll
      for (int q = 0; q < 4; q++) {
        float4 w = w4[q];
        acc[q*4+0] += xj * w.x; acc[q*4+1] += xj * w.y;
        acc[q*4+2] += xj * w.z; acc[q*4+3] += xj * w.w;
      }
    }
  }
#pragma unroll
  for (int off = 32; off >= 1; off >>= 1)
#pragma unroll
    for (int e = 0; e < 16; e++) acc[e] += __shfl_xor(acc[e], off, 64);

  if (l == 0) {
    float s[16], sc[16];
#pragma unroll
    for (int e = 0; e < 16; e++) {
      s[e] = 1.f / (1.f + __expf(-acc[e]));       // sigmoid scores (weights)
      sc[e] = s[e] + ebias[e];                     // biased (selection only)
    }
    float gs[4];
#pragma unroll
    for (int g = 0; g < 4; g++) {                  // sum of top-2 per group of 4
      float a = -1e30f, b2 = -1e30f;
#pragma unroll
      for (int j = 0; j < 4; j++) {
        float v = sc[g*4 + j];
        if (v > a) { b2 = a; a = v; } else if (v > b2) { b2 = v; }
      }
      gs[g] = a + b2;
    }
    int g1 = 0;
    for (int g = 1; g < 4; g++) if (gs[g] > gs[g1]) g1 = g;   // ties -> lowest idx
    int g2 = -1;
    for (int g = 0; g < 4; g++) if (g != g1 && (g2 < 0 || gs[g] > gs[g2])) g2 = g;
    float masked[16];
#pragma unroll
    for (int e = 0; e < 16; e++) {
      int g = e >> 2;
      masked[e] = (g == g1 || g == g2) ? sc[e] : 0.0f;        // ref: unselected -> 0.0
    }
    int idx[4]; float wv[4]; float denom = 1e-20f;
#pragma unroll
    for (int j = 0; j < 4; j++) {
      int best = 0; float bv = masked[0];
      for (int e = 1; e < 16; e++) if (masked[e] > bv) { bv = masked[e]; best = e; }
      idx[j] = best; wv[j] = s[best]; denom += s[best];
      masked[best] = -1e30f;
    }
#pragma unroll
    for (int j = 0; j < 4; j++) {
      topk_i[t * 4 + j] = idx[j];
      topk_w[t * 4 + j] = wv[j] / denom * 2.5f;   // fold ROUTED_SCALE
    }
  }
}

// =============== scatter: per-expert lists + 128-row tiles + slot map ===============
__global__ __launch_bounds__(1024) void scatter_kernel(
    const int* __restrict__ tki,
    int* __restrict__ tok, int* __restrict__ slotmap,
    int* __restrict__ tile_e, int* __restrict__ tile_srow,
    int* __restrict__ tile_hb, int* __restrict__ ntl) {
  __shared__ int lcnt[NEXP], lpos[NEXP], lbase[NEXP];
  int t = threadIdx.x;                   // one thread per token
  if (t < NEXP) { lcnt[t] = 0; lpos[t] = 0; }
  __syncthreads();
  int idx[4];
#pragma unroll
  for (int j = 0; j < 4; j++) idx[j] = tki[t*4+j];
#pragma unroll
  for (int j = 0; j < 4; j++) atomicAdd(&lcnt[idx[j]], 1);
  __syncthreads();
  if (t == 0) {                          // tile metadata (tiny serial)
    int total = 0, slots = 0;
    for (int e = 0; e < NEXP; e++) {
      int c = lcnt[e], nt = (c + 127) >> 7;
      lbase[e] = slots;
      for (int j = 0; j < nt; j++) {
        tile_e[total] = e; tile_srow[total] = j * 128; tile_hb[total] = slots + j * 128; total++;
      }
      slots += nt * 128;
    }
    ntl[0] = total;
  }
  __syncthreads();
#pragma unroll
  for (int j = 0; j < 4; j++) {
    int slot = atomicAdd(&lpos[idx[j]], 1);
    tok[idx[j] * T_TOK + slot] = t;
    slotmap[t * 4 + j] = lbase[idx[j]] + slot;   // hbuf/odown row of this assignment
  }
  __syncthreads();
  // padding rows (up to 127/expert) gather token 0; results never read by combine
  int e = t >> 6, s = t & 63;
  int c = lcnt[e];
  int top = ((c + 127) >> 7) << 7;
  for (int s2 = c + s; s2 < top; s2 += 64) tok[e * T_TOK + s2] = 0;
}

// =============== GEMM cores ===============
__device__ __forceinline__ f32x4 mfma16(f16x8 a, f16x8 b, f32x4 c) {
  return __builtin_amdgcn_mfma_f32_16x16x32_f16(a, b, c, 0, 0, 0);
}

// gate+up, TM=128 TN=64 BK=64, 4 waves 2x2 (wave = 64m x 32n), fused silu.
// shared: blocks 0..127; routed gather: blocks 128..511 (48 tiles x 8 nblk)
__global__ __launch_bounds__(256) void gu_all(
    const f16* __restrict__ xh,
    const f16* __restrict__ sgT, const f16* __restrict__ suT, f16* __restrict__ hsh,
    const f16* __restrict__ wgT, const f16* __restrict__ wuT, f16* __restrict__ hbuf,
    const int* __restrict__ tile_e, const int* __restrict__ tile_srow,
    const int* __restrict__ tile_hb, const int* __restrict__ ntl,
    const int* __restrict__ tok) {
  int b = blockIdx.x;
  const f16 *Bg, *Bu; f16* Hdst;
  int e = 0, srow = 0, mbase, n0, N;
  bool gather = (b >= 128);
  if (!gather) {
    Bg = sgT; Bu = suT; Hdst = hsh; N = ISH;
    mbase = (b >> 4) * 128; n0 = (b & 15) * 64;
  } else {
    int rb = b - 128, by = rb >> 3;
    if (by >= ntl[0]) return;
    e = tile_e[by]; srow = tile_srow[by]; mbase = tile_hb[by];
    size_t bo = (size_t)e * IDIM * HDIM;
    Bg = wgT + bo; Bu = wuT + bo; Hdst = hbuf; N = IDIM;
    n0 = (rb & 7) * 64;
  }
  const int K = HDIM;

  __shared__ f16 As[128 * 64], Bgs[64 * 64], Bus[64 * 64];   // 32 KB

  int tid = threadIdx.x, lane = tid & 63, wave = tid >> 6;
  int quad = lane >> 4, l15 = lane & 15;
  int r = lane >> 3, p = lane & 7;

  // 32 staging instrs: A:16 (rows 0..127), Bg:8, Bu:8 -> 8 per wave
  const f16* gb[8]; f16* lb[8];
#pragma unroll
  for (int jj = 0; jj < 8; jj++) {
    int j = wave * 8 + jj;
    int kcol = (p ^ r) << 3;                       // swizzled k-chunk
    if (j < 16) {
      int row = j * 8 + r;
      int grow = gather ? tok[e * T_TOK + srow + row] : (mbase + row);
      gb[jj] = xh + (size_t)grow * K + kcol;       lb[jj] = (f16*)As + (j << 9);
    } else if (j < 24) {
      int i = j - 16, row = i * 8 + r;
      gb[jj] = Bg + (size_t)(n0 + row) * K + kcol; lb[jj] = (f16*)Bgs + (i << 9);
    } else {
      int i = j - 24, row = i * 8 + r;
      gb[jj] = Bu + (size_t)(n0 + row) * K + kcol; lb[jj] = (f16*)Bus + (i << 9);
    }
  }

  int wr = wave >> 1, wc = wave & 1;               // wave tile: 64m x 32n
  f32x4 zero = {0.f, 0.f, 0.f, 0.f};
  f32x4 aG[4][2], aU[4][2];
#pragma unroll
  for (int mi = 0; mi < 4; mi++)
#pragma unroll
    for (int ni = 0; ni < 2; ni++) { aG[mi][ni] = zero; aU[mi][ni] = zero; }

  for (int kt = 0; kt < K; kt += 64) {
    __syncthreads();
#pragma unroll
    for (int jj = 0; jj < 8; jj++) gld16(gb[jj] + kt, lb[jj]);
    __syncthreads();
#pragma unroll
    for (int ks = 0; ks < 2; ks++) {
      int lch = (ks << 2) + quad;
      f16x8 a[4], g[2], u[2];
#pragma unroll
      for (int mi = 0; mi < 4; mi++) a[mi] = ldsfrag(As, 64 * wr + 16 * mi + l15, lch);
#pragma unroll
      for (int ni = 0; ni < 2; ni++) {
        g[ni] = ldsfrag(Bgs, 32 * wc + 16 * ni + l15, lch);
        u[ni] = ldsfrag(Bus, 32 * wc + 16 * ni + l15, lch);
      }
#pragma unroll
      for (int mi = 0; mi < 4; mi++)
#pragma unroll
        for (int ni = 0; ni < 2; ni++) {
          aG[mi][ni] = mfma16(a[mi], g[ni], aG[mi][ni]);
          aU[mi][ni] = mfma16(a[mi], u[ni], aU[mi][ni]);
        }
    }
  }
#pragma unroll
  for (int mi = 0; mi < 4; mi++)
#pragma unroll
    for (int ni = 0; ni < 2; ni++)
#pragma unroll
      for (int rg = 0; rg < 4; rg++) {
        int m = 64 * wr + 16 * mi + (quad << 2) + rg;   // C/D: row = quad*4+reg
        int n = n0 + 32 * wc + 16 * ni + l15;           //      col = lane&15
        float g = aG[mi][ni][rg], u = aU[mi][ni][rg];
        float val = (g / (1.f + __expf(-g))) * u;
        Hdst[(size_t)(mbase + m) * N + n] = (f16)val;
      }
}

// down proj, TM=128 TN=128 BK=64, 4 waves 2x2 (wave = 64x64).
// shared: blocks 0..63 -> out fp32; routed: blocks 64..447 -> odown f16
__global__ __launch_bounds__(256) void down_all(
    const f16* __restrict__ hsh, const f16* __restrict__ sdT,
    const f16* __restrict__ hbuf, const f16* __restrict__ wdT,
    float* __restrict__ out, f16* __restrict__ odown,
    const int* __restrict__ tile_hb, const int* __restrict__ tile_e,
    const int* __restrict__ ntl) {
  int b = blockIdx.x;
  bool routed = (b >= 64);
  const f16 *A, *B; int K, abase, n0;
  if (!routed) {
    A = hsh; B = sdT; K = ISH;
    abase = (b >> 3) * 128; n0 = (b & 7) * 128;
  } else {
    int rb = b - 64, by = rb >> 3;
    if (by >= ntl[0]) return;
    abase = tile_hb[by];
    A = hbuf; B = wdT + (size_t)tile_e[by] * HDIM * IDIM; K = IDIM;
    n0 = (rb & 7) * 128;
  }

  __shared__ f16 As[128 * 64], Bs[128 * 64];       // 32 KB

  int tid = threadIdx.x, lane = tid & 63, wave = tid >> 6;
  int quad = lane >> 4, l15 = lane & 15;
  int r = lane >> 3, p = lane & 7;

  // 32 staging instrs: A:16, B:16 -> 8 per wave
  const f16* gb[8]; f16* lb[8];
#pragma unroll
  for (int jj = 0; jj < 8; jj++) {
    int j = wave * 8 + jj;
    int kcol = (p ^ r) << 3;
    if (j < 16) {
      int row = j * 8 + r;
      gb[jj] = A + (size_t)(abase + row) * K + kcol; lb[jj] = (f16*)As + (j << 9);
    } else {
      int i = j - 16, row = i * 8 + r;
      gb[jj] = B + (size_t)(n0 + row) * K + kcol;    lb[jj] = (f16*)Bs + (i << 9);
    }
  }

  int wr = wave >> 1, wc = wave & 1;               // wave tile: 64 x 64
  f32x4 zero = {0.f, 0.f, 0.f, 0.f};
  f32x4 ac[4][4];
#pragma unroll
  for (int mi = 0; mi < 4; mi++)
#pragma unroll
    for (int ni = 0; ni < 4; ni++) ac[mi][ni] = zero;

  for (int kt = 0; kt < K; kt += 64) {
    __syncthreads();
#pragma unroll
    for (int jj = 0; jj < 8; jj++) gld16(gb[jj] + kt, lb[jj]);
    __syncthreads();
#pragma unroll
    for (int ks = 0; ks < 2; ks++) {
      int lch = (ks << 2) + quad;
      f16x8 a[4], bb[4];
#pragma unroll
      for (int mi = 0; mi < 4; mi++) a[mi] = ldsfrag(As, 64 * wr + 16 * mi + l15, lch);
#pragma unroll
      for (int ni = 0; ni < 4; ni++) bb[ni] = ldsfrag(Bs, 64 * wc + 16 * ni + l15, lch);
#pragma unroll
      for (int mi = 0; mi < 4; mi++)
#pragma unroll
        for (int ni = 0; ni < 4; ni++)
          ac[mi][ni] = mfma16(a[mi], bb[ni], ac[mi][ni]);
    }
  }
#pragma unroll
  for (int mi = 0; mi < 4; mi++)
#pragma unroll
    for (int ni = 0; ni < 4; ni++)
#pragma unroll
      for (int rg = 0; rg < 4; rg++) {
        int m = 64 * wr + 16 * mi + (quad << 2) + rg;
        int n = n0 + 64 * wc + 16 * ni + l15;
        if (routed) odown[(size_t)(abase + m) * HDIM + n] = (f16)ac[mi][ni][rg];
        else        out  [(size_t)(abase + m) * HDIM + n] = ac[mi][ni][rg];
      }
}

// =============== combine: out[t] += sum_j w_j * odown[slot(t,j)] ===============
__global__ __launch_bounds__(256) void combine_kernel(
    const f16* __restrict__ odown, const int* __restrict__ slotmap,
    const float* __restrict__ tkw, float* __restrict__ out) {
  int t = blockIdx.x;
  __shared__ int ss[4]; __shared__ float sw[4];
  if (threadIdx.x < 4) {
    ss[threadIdx.x] = slotmap[t * 4 + threadIdx.x];
    sw[threadIdx.x] = tkw[t * 4 + threadIdx.x];
  }
  __syncthreads();
  int h = threadIdx.x * 4;
  float4 acc = *(const float4*)(out + (size_t)t * HDIM + h);
#pragma unroll
  for (int j = 0; j < 4; j++) {
    f16x4 v = *(const f16x4*)(odown + (size_t)ss[j] * HDIM + h);
    float wj = sw[j];
    acc.x += wj * (float)v[0]; acc.y += wj * (float)v[1];
    acc.z += wj * (float)v[2]; acc.w += wj * (float)v[3];
  }
  *(float4*)(out + (size_t)t * HDIM + h) = acc;
}

// =============== launch ===============
extern "C" void kernel_launch(void* const* d_in, const int* in_sizes, int n_in,
                              void* d_out, int out_size, void* d_ws, size_t ws_size,
                              hipStream_t stream) {
  const float* x  = (const float*)d_in[0];
  const float* rw = (const float*)d_in[1];
  const float* eb = (const float*)d_in[2];
  const float* wg = (const float*)d_in[3];
  const float* wu = (const float*)d_in[4];
  const float* wd = (const float*)d_in[5];
  const float* sg = (const float*)d_in[6];
  const float* su = (const float*)d_in[7];
  const float* sd = (const float*)d_in[8];
  float* out = (float*)d_out;
  (void)in_sizes; (void)n_in; (void)out_size; (void)ws_size;

  char* w = (char*)d_ws;
  size_t off = 0;
  auto alloc = [&](size_t b) { void* p = w + off; off = (off + b + 255) & ~(size_t)255; return p; };

  f16* xh   = (f16*)alloc((size_t)T_TOK * HDIM * 2);
  f16* wgT  = (f16*)alloc((size_t)NEXP * IDIM * HDIM * 2);
  f16* wuT  = (f16*)alloc((size_t)NEXP * IDIM * HDIM * 2);
  f16* wdT  = (f16*)alloc((size_t)NEXP * HDIM * IDIM * 2);
  f16* sgT  = (f16*)alloc((size_t)ISH * HDIM * 2);
  f16* suT  = (f16*)alloc((size_t)ISH * HDIM * 2);
  f16* sdT  = (f16*)alloc((size_t)HDIM * ISH * 2);
  f16* hbuf = (f16*)alloc((size_t)HSLOTS * IDIM * 2);
  f16* hsh  = (f16*)alloc((size_t)T_TOK * ISH * 2);
  int* topk_i = (int*)alloc((size_t)T_TOK * 4 * 4);
  float* topk_w = (float*)alloc((size_t)T_TOK * 4 * 4);
  int* tok  = (int*)alloc((size_t)NEXP * T_TOK * 4);
  int* slotmap = (int*)alloc((size_t)T_TOK * 4 * 4);
  int* tile_e    = (int*)alloc(MAXT128 * 4);
  int* tile_srow = (int*)alloc(MAXT128 * 4);
  int* tile_hb   = (int*)alloc(MAXT128 * 4);
  int* ntl       = (int*)alloc(16);
  // odown (f16, HSLOTS x HDIM = 12.6 MB) aliases wgT (16 MB): wgT dead after gu_all.
  f16* odown = (f16*)wgT;

  // transpose (1728 blocks) + router (256 blocks) in one dispatch
  prep_all<<<NTTILES + T_TOK / 4, 256, 0, stream>>>(
      wg, wu, wd, sg, su, sd, wgT, wuT, wdT, sgT, suT, sdT,
      x, rw, eb, xh, topk_i, topk_w);
  scatter_kernel<<<1, 1024, 0, stream>>>(topk_i, tok, slotmap,
                                         tile_e, tile_srow, tile_hb, ntl);
  // shared gu (128 blocks) + routed gu (384) in one dispatch
  gu_all<<<128 + MAXT128 * 8, 256, 0, stream>>>(
      xh, sgT, suT, hsh, wgT, wuT, hbuf, tile_e, tile_srow, tile_hb, ntl, tok);
  // shared down (64) -> out fp32; routed down (384) -> odown f16
  down_all<<<64 + MAXT128 * 8, 256, 0, stream>>>(
      hsh, sdT, hbuf, wdT, out, odown, tile_hb, tile_e, ntl);
  // out[t] += sum_j w_j * odown[slot]
  combine_kernel<<<T_TOK, 256, 0, stream>>>(odown, slotmap, topk_w, out);
}

// Round 7
// 228.005 us; speedup vs baseline: 1.0087x; 1.0049x over previous
//
#include <hip/hip_runtime.h>
#include <stdint.h>

// Problem constants (match reference)
#define T_TOK 1024
#define HDIM  1024
#define IDIM  512
#define NEXP  16
#define ISH   1024       // shared intermediate
#define MAXT128  48      // sum ceil(cnt_e/128) <= 4096/128 + 16 = 48
#define HSLOTS   6144    // 48 * 128 padded routed rows

typedef _Float16 f16;
typedef __attribute__((ext_vector_type(8))) _Float16 f16x8;
typedef __attribute__((ext_vector_type(4))) _Float16 f16x4;
typedef __attribute__((ext_vector_type(4))) float    f32x4;

// ---- async global->LDS, 16B per lane. LDS dst is wave-uniform base; HW adds lane*16.
__device__ __forceinline__ void gld16(const void* g, void* l) {
  __builtin_amdgcn_global_load_lds(
      (__attribute__((address_space(1))) void*)(uintptr_t)g,
      (__attribute__((address_space(3))) void*)(uint32_t)(uintptr_t)l,
      16, 0, 0);
}

// ---- A-tile LDS: rows of 64 halfs, 16B chunks XOR-swizzled by (row&7) (gld16-compatible)
__device__ __forceinline__ f16x8 ldsfragA(const f16* buf, int row, int lch) {
  int phys = lch ^ (row & 7);
  return *(const f16x8*)(buf + row * 64 + phys * 8);
}

// ---- B-tile LDS: n-rows of 64 halfs k-contig, stride 72 f16 (144B, 16B-mult),
// 16B chunk position XOR-swizzled by (n>>3)&7. Writes (one chunk-col per wave)
// and b128 frag reads are both bank-uniform (8 dwords/bank = b128 minimum).
__device__ __forceinline__ f16x8 ldsfragB(const f16* buf, int n, int kc) {
  int c = kc ^ ((n >> 3) & 7);
  return *(const f16x8*)(buf + n * 72 + c * 8);
}

// stage one 64k x 64n fp32 [K,N]-layout tile -> f16 k-contig LDS (all 256 threads)
__device__ __forceinline__ void stageB(const float* __restrict__ W, int ldW,
                                       int kt, int n0, f16* __restrict__ Bs,
                                       int nbase, int tid) {
  int p = tid & 31, kg = tid >> 5;            // p: n-pair 0..31, kg: k-oct 0..7
  int n = 2 * p;
  const float* src = W + (size_t)(kt + 8 * kg) * ldW + n0 + n;
  float2 v[8];
#pragma unroll
  for (int r = 0; r < 8; r++) v[r] = *(const float2*)(src + (size_t)r * ldW);
  f16x8 c0, c1;
#pragma unroll
  for (int r = 0; r < 8; r++) { c0[r] = (f16)v[r].x; c1[r] = (f16)v[r].y; }
  int nn = nbase + n;
  int cc = kg ^ ((nn >> 3) & 7);              // nn even -> same chunk for nn+1
  *(f16x8*)(Bs + (size_t)nn * 72 + cc * 8) = c0;
  *(f16x8*)(Bs + (size_t)(nn + 1) * 72 + cc * 8) = c1;
}

// =============== router GEMV (also emits xh = f16(x)): 4 tokens/block ===============
__global__ __launch_bounds__(256) void router_kernel(
    const float* __restrict__ x, const float* __restrict__ rw, const float* __restrict__ ebias,
    f16* __restrict__ xh, int* __restrict__ topk_i, float* __restrict__ topk_w) {
  int wave = threadIdx.x >> 6, l = threadIdx.x & 63;
  int t = blockIdx.x * 4 + wave;
  float acc[16];
#pragma unroll
  for (int e = 0; e < 16; e++) acc[e] = 0.f;
#pragma unroll
  for (int i = 0; i < 4; i++) {
    int k = i * 256 + l * 4;
    float4 xv = *(const float4*)(x + (size_t)t * HDIM + k);
    f16x4 h = { (f16)xv.x, (f16)xv.y, (f16)xv.z, (f16)xv.w };
    *(f16x4*)(xh + (size_t)t * HDIM + k) = h;
    const float* xp = &xv.x;
#pragma unroll
    for (int j = 0; j < 4; j++) {
      float xj = xp[j];
      const float4* w4 = (const float4*)(rw + (size_t)(k + j) * 16);
#pragma unroll
      for (int q = 0; q < 4; q++) {
        float4 w = w4[q];
        acc[q*4+0] += xj * w.x; acc[q*4+1] += xj * w.y;
        acc[q*4+2] += xj * w.z; acc[q*4+3] += xj * w.w;
      }
    }
  }
#pragma unroll
  for (int off = 32; off >= 1; off >>= 1)
#pragma unroll
    for (int e = 0; e < 16; e++) acc[e] += __shfl_xor(acc[e], off, 64);

  if (l == 0) {
    float s[16], sc[16];
#pragma unroll
    for (int e = 0; e < 16; e++) {
      s[e] = 1.f / (1.f + __expf(-acc[e]));       // sigmoid scores (weights)
      sc[e] = s[e] + ebias[e];                     // biased (selection only)
    }
    float gs[4];
#pragma unroll
    for (int g = 0; g < 4; g++) {                  // sum of top-2 per group of 4
      float a = -1e30f, b2 = -1e30f;
#pragma unroll
      for (int j = 0; j < 4; j++) {
        float v = sc[g*4 + j];
        if (v > a) { b2 = a; a = v; } else if (v > b2) { b2 = v; }
      }
      gs[g] = a + b2;
    }
    int g1 = 0;
    for (int g = 1; g < 4; g++) if (gs[g] > gs[g1]) g1 = g;   // ties -> lowest idx
    int g2 = -1;
    for (int g = 0; g < 4; g++) if (g != g1 && (g2 < 0 || gs[g] > gs[g2])) g2 = g;
    float masked[16];
#pragma unroll
    for (int e = 0; e < 16; e++) {
      int g = e >> 2;
      masked[e] = (g == g1 || g == g2) ? sc[e] : 0.0f;        // ref: unselected -> 0.0
    }
    int idx[4]; float wv[4]; float denom = 1e-20f;
#pragma unroll
    for (int j = 0; j < 4; j++) {
      int best = 0; float bv = masked[0];
      for (int e = 1; e < 16; e++) if (masked[e] > bv) { bv = masked[e]; best = e; }
      idx[j] = best; wv[j] = s[best]; denom += s[best];
      masked[best] = -1e30f;
    }
#pragma unroll
    for (int j = 0; j < 4; j++) {
      topk_i[t * 4 + j] = idx[j];
      topk_w[t * 4 + j] = wv[j] / denom * 2.5f;   // fold ROUTED_SCALE
    }
  }
}

// =============== scatter: per-expert lists + 128-row tiles + slot map ===============
__global__ __launch_bounds__(1024) void scatter_kernel(
    const int* __restrict__ tki,
    int* __restrict__ tok, int* __restrict__ slotmap,
    int* __restrict__ tile_e, int* __restrict__ tile_srow,
    int* __restrict__ tile_hb, int* __restrict__ ntl) {
  __shared__ int lcnt[NEXP], lpos[NEXP], lbase[NEXP];
  int t = threadIdx.x;                   // one thread per token
  if (t < NEXP) { lcnt[t] = 0; lpos[t] = 0; }
  __syncthreads();
  int idx[4];
#pragma unroll
  for (int j = 0; j < 4; j++) idx[j] = tki[t*4+j];
#pragma unroll
  for (int j = 0; j < 4; j++) atomicAdd(&lcnt[idx[j]], 1);
  __syncthreads();
  if (t == 0) {                          // tile metadata (tiny serial)
    int total = 0, slots = 0;
    for (int e = 0; e < NEXP; e++) {
      int c = lcnt[e], nt = (c + 127) >> 7;
      lbase[e] = slots;
      for (int j = 0; j < nt; j++) {
        tile_e[total] = e; tile_srow[total] = j * 128; tile_hb[total] = slots + j * 128; total++;
      }
      slots += nt * 128;
    }
    ntl[0] = total;
  }
  __syncthreads();
#pragma unroll
  for (int j = 0; j < 4; j++) {
    int slot = atomicAdd(&lpos[idx[j]], 1);
    tok[idx[j] * T_TOK + slot] = t;
    slotmap[t * 4 + j] = lbase[idx[j]] + slot;   // hbuf/odown row of this assignment
  }
  __syncthreads();
  // padding rows (up to 127/expert) gather token 0; results never read by combine
  int e = t >> 6, s = t & 63;
  int c = lcnt[e];
  int top = ((c + 127) >> 7) << 7;
  for (int s2 = c + s; s2 < top; s2 += 64) tok[e * T_TOK + s2] = 0;
}

// =============== GEMM cores ===============
__device__ __forceinline__ f32x4 mfma16(f16x8 a, f16x8 b, f32x4 c) {
  return __builtin_amdgcn_mfma_f32_16x16x32_f16(a, b, c, 0, 0, 0);
}

// gate+up, TM=128 TN=64 BK=64, 4 waves 2x2 (wave = 64m x 32n), fused silu.
// B staged DIRECTLY from fp32 [K,N] weights (no pre-transpose).
// shared: blocks 0..127; routed gather: blocks 128..511 (48 tiles x 8 nblk)
__global__ __launch_bounds__(256) void gu_all(
    const f16* __restrict__ xh,
    const float* __restrict__ sg, const float* __restrict__ su, f16* __restrict__ hsh,
    const float* __restrict__ wg, const float* __restrict__ wu, f16* __restrict__ hbuf,
    const int* __restrict__ tile_e, const int* __restrict__ tile_srow,
    const int* __restrict__ tile_hb, const int* __restrict__ ntl,
    const int* __restrict__ tok) {
  int b = blockIdx.x;
  const float *Bg, *Bu; f16* Hdst;
  int e = 0, srow = 0, mbase, n0, N;
  bool gather = (b >= 128);
  if (!gather) {
    Bg = sg; Bu = su; Hdst = hsh; N = ISH;
    mbase = (b >> 4) * 128; n0 = (b & 15) * 64;
  } else {
    int rb = b - 128, by = rb >> 3;
    if (by >= ntl[0]) return;
    e = tile_e[by]; srow = tile_srow[by]; mbase = tile_hb[by];
    size_t bo = (size_t)e * HDIM * IDIM;
    Bg = wg + bo; Bu = wu + bo; Hdst = hbuf; N = IDIM;
    n0 = (rb & 7) * 64;
  }
  const int K = HDIM;

  __shared__ f16 As[128 * 64];         // 16 KB, gld16 XOR layout
  __shared__ f16 Bgs[64 * 72], Bus[64 * 72];   // 9 KB each, stride-72 layout

  int tid = threadIdx.x, lane = tid & 63, wave = tid >> 6;
  int quad = lane >> 4, l15 = lane & 15;
  int r = lane >> 3, p = lane & 7;

  // A staging: 16 gld16 (rows 0..127), 4 per wave
  const f16* gbA[4]; f16* lbA[4];
#pragma unroll
  for (int jj = 0; jj < 4; jj++) {
    int j = wave * 4 + jj;
    int kcol = (p ^ r) << 3;                       // swizzled k-chunk
    int row = j * 8 + r;
    int grow = gather ? tok[e * T_TOK + srow + row] : (mbase + row);
    gbA[jj] = xh + (size_t)grow * K + kcol;
    lbA[jj] = (f16*)As + (j << 9);
  }

  int wr = wave >> 1, wc = wave & 1;               // wave tile: 64m x 32n
  f32x4 zero = {0.f, 0.f, 0.f, 0.f};
  f32x4 aG[4][2], aU[4][2];
#pragma unroll
  for (int mi = 0; mi < 4; mi++)
#pragma unroll
    for (int ni = 0; ni < 2; ni++) { aG[mi][ni] = zero; aU[mi][ni] = zero; }

  for (int kt = 0; kt < K; kt += 64) {
    __syncthreads();
#pragma unroll
    for (int jj = 0; jj < 4; jj++) gld16(gbA[jj] + kt, lbA[jj]);
    stageB(Bg, N, kt, n0, Bgs, 0, tid);
    stageB(Bu, N, kt, n0, Bus, 0, tid);
    __syncthreads();
#pragma unroll
    for (int ks = 0; ks < 2; ks++) {
      int lch = (ks << 2) + quad;
      f16x8 a[4], g[2], u[2];
#pragma unroll
      for (int mi = 0; mi < 4; mi++) a[mi] = ldsfragA(As, 64 * wr + 16 * mi + l15, lch);
#pragma unroll
      for (int ni = 0; ni < 2; ni++) {
        g[ni] = ldsfragB(Bgs, 32 * wc + 16 * ni + l15, lch);
        u[ni] = ldsfragB(Bus, 32 * wc + 16 * ni + l15, lch);
      }
#pragma unroll
      for (int mi = 0; mi < 4; mi++)
#pragma unroll
        for (int ni = 0; ni < 2; ni++) {
          aG[mi][ni] = mfma16(a[mi], g[ni], aG[mi][ni]);
          aU[mi][ni] = mfma16(a[mi], u[ni], aU[mi][ni]);
        }
    }
  }
#pragma unroll
  for (int mi = 0; mi < 4; mi++)
#pragma unroll
    for (int ni = 0; ni < 2; ni++)
#pragma unroll
      for (int rg = 0; rg < 4; rg++) {
        int m = 64 * wr + 16 * mi + (quad << 2) + rg;   // C/D: row = quad*4+reg
        int n = n0 + 32 * wc + 16 * ni + l15;           //      col = lane&15
        float g = aG[mi][ni][rg], u = aU[mi][ni][rg];
        float val = (g / (1.f + __expf(-g))) * u;
        Hdst[(size_t)(mbase + m) * N + n] = (f16)val;
      }
}

// down proj, TM=128 TN=128 BK=64, 4 waves 2x2 (wave = 64x64).
// B staged directly from fp32 [K,H] weights. shared: blocks 0..63 -> out fp32;
// routed: blocks 64..447 -> odown f16
__global__ __launch_bounds__(256) void down_all(
    const f16* __restrict__ hsh, const float* __restrict__ sd,
    const f16* __restrict__ hbuf, const float* __restrict__ wd,
    float* __restrict__ out, f16* __restrict__ odown,
    const int* __restrict__ tile_hb, const int* __restrict__ tile_e,
    const int* __restrict__ ntl) {
  int b = blockIdx.x;
  bool routed = (b >= 64);
  const f16* A; const float* B; int K, abase, n0;
  if (!routed) {
    A = hsh; B = sd; K = ISH;
    abase = (b >> 3) * 128; n0 = (b & 7) * 128;
  } else {
    int rb = b - 64, by = rb >> 3;
    if (by >= ntl[0]) return;
    abase = tile_hb[by];
    A = hbuf; B = wd + (size_t)tile_e[by] * IDIM * HDIM; K = IDIM;
    n0 = (rb & 7) * 128;
  }

  __shared__ f16 As[128 * 64];          // 16 KB
  __shared__ f16 Bs[128 * 72];          // 18 KB

  int tid = threadIdx.x, lane = tid & 63, wave = tid >> 6;
  int quad = lane >> 4, l15 = lane & 15;
  int r = lane >> 3, p = lane & 7;

  const f16* gbA[4]; f16* lbA[4];
#pragma unroll
  for (int jj = 0; jj < 4; jj++) {
    int j = wave * 4 + jj;
    int kcol = (p ^ r) << 3;
    int row = j * 8 + r;
    gbA[jj] = A + (size_t)(abase + row) * K + kcol;
    lbA[jj] = (f16*)As + (j << 9);
  }

  int wr = wave >> 1, wc = wave & 1;               // wave tile: 64 x 64
  f32x4 zero = {0.f, 0.f, 0.f, 0.f};
  f32x4 ac[4][4];
#pragma unroll
  for (int mi = 0; mi < 4; mi++)
#pragma unroll
    for (int ni = 0; ni < 4; ni++) ac[mi][ni] = zero;

  for (int kt = 0; kt < K; kt += 64) {
    __syncthreads();
#pragma unroll
    for (int jj = 0; jj < 4; jj++) gld16(gbA[jj] + kt, lbA[jj]);
    stageB(B, HDIM, kt, n0,      Bs, 0,  tid);     // n-subtile 0..63
    stageB(B, HDIM, kt, n0 + 64, Bs, 64, tid);     // n-subtile 64..127
    __syncthreads();
#pragma unroll
    for (int ks = 0; ks < 2; ks++) {
      int lch = (ks << 2) + quad;
      f16x8 a[4], bb[4];
#pragma unroll
      for (int mi = 0; mi < 4; mi++) a[mi] = ldsfragA(As, 64 * wr + 16 * mi + l15, lch);
#pragma unroll
      for (int ni = 0; ni < 4; ni++) bb[ni] = ldsfragB(Bs, 64 * wc + 16 * ni + l15, lch);
#pragma unroll
      for (int mi = 0; mi < 4; mi++)
#pragma unroll
        for (int ni = 0; ni < 4; ni++)
          ac[mi][ni] = mfma16(a[mi], bb[ni], ac[mi][ni]);
    }
  }
#pragma unroll
  for (int mi = 0; mi < 4; mi++)
#pragma unroll
    for (int ni = 0; ni < 4; ni++)
#pragma unroll
      for (int rg = 0; rg < 4; rg++) {
        int m = 64 * wr + 16 * mi + (quad << 2) + rg;
        int n = n0 + 64 * wc + 16 * ni + l15;
        if (routed) odown[(size_t)(abase + m) * HDIM + n] = (f16)ac[mi][ni][rg];
        else        out  [(size_t)(abase + m) * HDIM + n] = ac[mi][ni][rg];
      }
}

// =============== combine: out[t] += sum_j w_j * odown[slot(t,j)] ===============
__global__ __launch_bounds__(256) void combine_kernel(
    const f16* __restrict__ odown, const int* __restrict__ slotmap,
    const float* __restrict__ tkw, float* __restrict__ out) {
  int t = blockIdx.x;
  __shared__ int ss[4]; __shared__ float sw[4];
  if (threadIdx.x < 4) {
    ss[threadIdx.x] = slotmap[t * 4 + threadIdx.x];
    sw[threadIdx.x] = tkw[t * 4 + threadIdx.x];
  }
  __syncthreads();
  int h = threadIdx.x * 4;
  float4 acc = *(const float4*)(out + (size_t)t * HDIM + h);
#pragma unroll
  for (int j = 0; j < 4; j++) {
    f16x4 v = *(const f16x4*)(odown + (size_t)ss[j] * HDIM + h);
    float wj = sw[j];
    acc.x += wj * (float)v[0]; acc.y += wj * (float)v[1];
    acc.z += wj * (float)v[2]; acc.w += wj * (float)v[3];
  }
  *(float4*)(out + (size_t)t * HDIM + h) = acc;
}

// =============== launch ===============
extern "C" void kernel_launch(void* const* d_in, const int* in_sizes, int n_in,
                              void* d_out, int out_size, void* d_ws, size_t ws_size,
                              hipStream_t stream) {
  const float* x  = (const float*)d_in[0];
  const float* rw = (const float*)d_in[1];
  const float* eb = (const float*)d_in[2];
  const float* wg = (const float*)d_in[3];
  const float* wu = (const float*)d_in[4];
  const float* wd = (const float*)d_in[5];
  const float* sg = (const float*)d_in[6];
  const float* su = (const float*)d_in[7];
  const float* sd = (const float*)d_in[8];
  float* out = (float*)d_out;
  (void)in_sizes; (void)n_in; (void)out_size; (void)ws_size;

  char* w = (char*)d_ws;
  size_t off = 0;
  auto alloc = [&](size_t b) { void* p = w + off; off = (off + b + 255) & ~(size_t)255; return p; };

  f16* xh   = (f16*)alloc((size_t)T_TOK * HDIM * 2);
  f16* hbuf = (f16*)alloc((size_t)HSLOTS * IDIM * 2);
  f16* hsh  = (f16*)alloc((size_t)T_TOK * ISH * 2);
  f16* odown = (f16*)alloc((size_t)HSLOTS * HDIM * 2);
  int* topk_i = (int*)alloc((size_t)T_TOK * 4 * 4);
  float* topk_w = (float*)alloc((size_t)T_TOK * 4 * 4);
  int* tok  = (int*)alloc((size_t)NEXP * T_TOK * 4);
  int* slotmap = (int*)alloc((size_t)T_TOK * 4 * 4);
  int* tile_e    = (int*)alloc(MAXT128 * 4);
  int* tile_srow = (int*)alloc(MAXT128 * 4);
  int* tile_hb   = (int*)alloc(MAXT128 * 4);
  int* ntl       = (int*)alloc(16);

  router_kernel<<<T_TOK / 4, 256, 0, stream>>>(x, rw, eb, xh, topk_i, topk_w);
  scatter_kernel<<<1, 1024, 0, stream>>>(topk_i, tok, slotmap,
                                         tile_e, tile_srow, tile_hb, ntl);
  // shared gu (128 blocks) + routed gu (384) in one dispatch; B from fp32 weights
  gu_all<<<128 + MAXT128 * 8, 256, 0, stream>>>(
      xh, sg, su, hsh, wg, wu, hbuf, tile_e, tile_srow, tile_hb, ntl, tok);
  // shared down (64) -> out fp32; routed down (384) -> odown f16
  down_all<<<64 + MAXT128 * 8, 256, 0, stream>>>(
      hsh, sd, hbuf, wd, out, odown, tile_hb, tile_e, ntl);
  // out[t] += sum_j w_j * odown[slot]
  combine_kernel<<<T_TOK, 256, 0, stream>>>(odown, slotmap, topk_w, out);
}